// Round 6
// baseline (246.735 us; speedup 1.0000x reference)
//
#include <hip/hip_runtime.h>
#include <hip/hip_bf16.h>
#include <math.h>

#define Bb 4
#define Nn 4096
#define Hh 64
#define T1c 3072
#define MC 4           // split-m chunks (blocks); waves add 2x more split depth

typedef unsigned short ushort_t;
typedef __bf16 bf16x4 __attribute__((ext_vector_type(4)));
typedef __bf16 bf16x8 __attribute__((ext_vector_type(8)));
typedef float floatx4 __attribute__((ext_vector_type(4)));
typedef float floatx16 __attribute__((ext_vector_type(16)));

// Static device scratch, fully rewritten every call (no cross-call state).
__device__ ushort_t g_qw[(size_t)Bb * Nn * Hh];
__device__ ushort_t g_kw[(size_t)Bb * Nn * Hh];
__device__ ushort_t g_vt[(size_t)Bb * Nn * Hh];   // [B][H][N] transposed V
__device__ ushort_t g_dt[(size_t)Bb * Nn * Hh];
__device__ unsigned long long g_bm[(size_t)Nn * (Nn / 64)]; // bit[n][m]: adjacency^T bits
__device__ float    g_pac[(size_t)Bb * 64 * MC * 64 * 64]; // partial acc [b][nt][mc][n][d]
__device__ float    g_pss[(size_t)Bb * 64 * MC * 64];      // partial ssq [b][nt][mc][n]

__device__ __forceinline__ float bf2f(unsigned short u) {
    union { unsigned int i; float f; } c;
    c.i = ((unsigned int)u) << 16;
    return c.f;
}
__device__ __forceinline__ unsigned short f2bf(float f) {
    union { float f; unsigned int i; } c;
    c.f = f;
    unsigned int x = c.i;
    unsigned int r = (x + 0x7fffu + ((x >> 16) & 1u)) >> 16;  // RNE
    return (unsigned short)r;
}

// dtype-adaptive loaders (eidx = element index); F32 is the measured reality.
__device__ __forceinline__ bf16x8 ld8(const void* p, size_t eidx, bool f32) {
    if (f32) {
        const float* fp = (const float*)p + eidx;
        float4 x0 = *(const float4*)fp;
        float4 x1 = *(const float4*)(fp + 4);
        bf16x8 r;
        r[0] = (__bf16)x0.x; r[1] = (__bf16)x0.y; r[2] = (__bf16)x0.z; r[3] = (__bf16)x0.w;
        r[4] = (__bf16)x1.x; r[5] = (__bf16)x1.y; r[6] = (__bf16)x1.z; r[7] = (__bf16)x1.w;
        return r;
    }
    return *(const bf16x8*)((const ushort_t*)p + eidx);
}
__device__ __forceinline__ float ldS(const void* p, size_t eidx, bool f32) {
    return f32 ? ((const float*)p)[eidx] : bf2f(((const ushort_t*)p)[eidx]);
}
__device__ __forceinline__ void stOut(void* p, size_t eidx, float v, bool f32) {
    if (f32) ((float*)p)[eidx] = v;
    else ((ushort_t*)p)[eidx] = f2bf(v);
}

__device__ __forceinline__ floatx4 mfma16(bf16x8 a, bf16x8 b, floatx4 c) {
    return __builtin_amdgcn_mfma_f32_16x16x32_bf16(a, b, c, 0, 0, 0);
}
__device__ __forceinline__ floatx16 mfma32(bf16x8 a, bf16x8 b, floatx16 c) {
    return __builtin_amdgcn_mfma_f32_32x32x16_bf16(a, b, c, 0, 0, 0);
}
__device__ __forceinline__ bf16x8 cat44(bf16x4 lo, bf16x4 hi) {
    bf16x8 r;
    r[0] = lo[0]; r[1] = lo[1]; r[2] = lo[2]; r[3] = lo[3];
    r[4] = hi[0]; r[5] = hi[1]; r[6] = hi[2]; r[7] = hi[3];
    return r;
}

__device__ __forceinline__ float fast_tanh(float x) {
    float e = __expf(-2.0f * fabsf(x));
    float t = (1.0f - e) / (1.0f + e);
    return copysignf(t, x);
}

// ---------------------------------------------------------------------------
// Phase A: q,k,vT,dt. grid B*(N/16)=1024 blocks x 256 thr; waves split by output.
// ---------------------------------------------------------------------------
__global__ __launch_bounds__(256) void qkvt_kernel(
    const void* __restrict__ hid, const void* __restrict__ adj,
    const void* __restrict__ Wq, const void* __restrict__ Wk,
    const void* __restrict__ Wv,
    const void* __restrict__ Wti, const void* __restrict__ bti,
    const void* __restrict__ Wto, const void* __restrict__ bto)
{
    const bool F32 = (*(const unsigned*)adj) == 0x3F800000u;

    const int bi = blockIdx.x;
    const int b = bi >> 8;
    const int n16 = (bi & 255) << 4;
    const int t = threadIdx.x;
    const int wv = t >> 6, lane = t & 63, l16 = lane & 15, quad = lane >> 4;
    const bool inter = (n16 < T1c);

    const void* W = (wv == 0) ? Wq : (wv == 1) ? Wk : (wv == 2) ? Wv
                    : (inter ? Wti : Wto);
    const void* bt = inter ? bti : bto;

    const size_t hbase = ((size_t)(b * Nn + n16 + l16)) * Hh + quad * 8;
    bf16x8 a0 = ld8(hid, hbase, F32);
    bf16x8 a1 = ld8(hid, hbase + 32, F32);
    floatx4 z = {0.f, 0.f, 0.f, 0.f};

    floatx4 c[4];
#pragma unroll
    for (int ti = 0; ti < 4; ++ti) {
        const size_t wrow = (size_t)(ti * 16 + l16) * 64 + quad * 8;
        bf16x8 w0 = ld8(W, wrow, F32);
        bf16x8 w1 = ld8(W, wrow + 32, F32);
        c[ti] = mfma16(a1, w1, mfma16(a0, w0, z));
    }

    if (wv == 0 || wv == 1) {
        ushort_t* dst = (wv == 0) ? g_qw : g_kw;
#pragma unroll
        for (int ti = 0; ti < 4; ++ti)
#pragma unroll
            for (int r = 0; r < 4; ++r)
                dst[((size_t)(b * Nn + n16 + quad * 4 + r)) * 64 + ti * 16 + l16] = f2bf(c[ti][r]);
    } else if (wv == 2) {
#pragma unroll
        for (int ti = 0; ti < 4; ++ti) {
            uint2 pk;
            pk.x = (unsigned)f2bf(c[ti][0]) | ((unsigned)f2bf(c[ti][1]) << 16);
            pk.y = (unsigned)f2bf(c[ti][2]) | ((unsigned)f2bf(c[ti][3]) << 16);
            *(uint2*)&g_vt[((size_t)(b * 64 + ti * 16 + l16)) * Nn + n16 + quad * 4] = pk;
        }
    } else {
#pragma unroll
        for (int ti = 0; ti < 4; ++ti) {
            const float btv = ldS(bt, ti * 16 + l16, F32);
#pragma unroll
            for (int r = 0; r < 4; ++r)
                g_dt[((size_t)(b * Nn + n16 + quad * 4 + r)) * 64 + ti * 16 + l16] =
                    f2bf(fast_tanh(0.5f * (c[ti][r] + btv)));
        }
    }
}

// ---------------------------------------------------------------------------
// Phase A2: transposed adjacency bitmask. bit[n][m] = (adjacency[m][n] != 0).
// grid 1024 blocks x 256 thr; block (mt, nc): m-tile of 64 rows (lanes),
// wave w scans n in [nc*256 + w*64, +64). ballot across lanes = across m.
// ---------------------------------------------------------------------------
__global__ __launch_bounds__(256) void bm_kernel(const void* __restrict__ adj)
{
    const bool F32 = (*(const unsigned*)adj) == 0x3F800000u;
    const int bi = blockIdx.x;
    const int mt = bi & 63;
    const int nc = bi >> 6;
    const int w = threadIdx.x >> 6, lane = threadIdx.x & 63;
    const int n0 = nc * 256 + w * 64;
    const size_t rowoff = (size_t)(mt * 64 + lane) * Nn;

    for (int j = 0; j < 64; ++j) {
        const int n = n0 + j;
        const float v = ldS(adj, rowoff + n, F32);
        const unsigned long long m = __ballot(v != 0.f);
        if (lane == 0) g_bm[(size_t)n * 64 + mt] = m;
    }
}

// ---------------------------------------------------------------------------
// Phase B: split-m attention partials, transpose-free.
// S' = K·Q^T via mfma32 (C: lane=n, regs=m) -> masked S packs DIRECTLY into
// PV A-frags in-lane (af[c][j] = sm[8c+j]); V B-frags absorb the m-permutation
// as 2x ds_read_b64. Wave (nh, mh): n-half nh, m-half mh (split depth 2 within
// block, combined through LDS at the end so g_pac stays MC=4).
// grid B*64*MC = 1024 blocks x 256 thr.
// ---------------------------------------------------------------------------
__global__ __launch_bounds__(256, 4) void attn_part_kernel()
{
    __shared__ __align__(16) unsigned char smem[64 * 72 * 2 * 2 + 256];
    ushort_t* kT  = (ushort_t*)smem;            // [64][72] K tile [m][h]
    ushort_t* vTl = kT + 64 * 72;               // [64][72] V^T tile [d][m]
    // after the loop, smem is reused: accbuf [2][32][64] fp32 + ssqbuf [2][32]

    const unsigned* bm32 = (const unsigned*)g_bm;

    const int bi = blockIdx.x;
    const int b  = bi >> 8;          // b-variants 256 apart -> same XCD for L2 reuse
    const int mc = bi & 3;
    const int nt = (bi >> 2) & 63;
    const int n0 = nt << 6;
    const int t = threadIdx.x;
    const int wv = t >> 6, lane = t & 63;
    const int l32 = lane & 31, h = lane >> 5;
    const int nh = wv >> 1, mh = wv & 1;

    // Q fragments (B-operand of K·Q^T): lane = n, k = h*8 + 16*i + e
    bf16x8 qf[4];
#pragma unroll
    for (int i = 0; i < 4; ++i)
        qf[i] = *(const bf16x8*)&g_qw[((size_t)(b * Nn + n0 + nh * 32 + l32)) * 64 + h * 8 + 16 * i];

    floatx16 acc[2];
#pragma unroll
    for (int dt = 0; dt < 2; ++dt)
#pragma unroll
        for (int r = 0; r < 16; ++r) acc[dt][r] = 0.f;
    float ssql = 0.f;

    int srow[2], scol[2];
#pragma unroll
    for (int i = 0; i < 2; ++i) { const int cc = t + 256 * i; srow[i] = cc >> 3; scol[i] = (cc & 7) * 8; }

    for (int it = 0; it < 16; ++it) {
        const int m0 = mc * 1024 + it * 64;

        // stage K-tile and V^T-tile
#pragma unroll
        for (int i = 0; i < 2; ++i) {
            *(bf16x8*)&kT[srow[i] * 72 + scol[i]] =
                *(const bf16x8*)&g_kw[((size_t)(b * Nn + m0 + srow[i])) * 64 + scol[i]];
            *(bf16x8*)&vTl[srow[i] * 72 + scol[i]] =
                *(const bf16x8*)&g_vt[((size_t)(b * 64 + srow[i])) * Nn + m0 + scol[i]];
        }
        __syncthreads();

        // S' = K·Q^T: A = K (lane=m), B = Q (lane=n); D: lane=n, regs=m
        floatx16 s;
#pragma unroll
        for (int r = 0; r < 16; ++r) s[r] = 0.f;
#pragma unroll
        for (int i = 0; i < 4; ++i) {
            bf16x8 kf = *(const bf16x8*)&kT[(mh * 32 + l32) * 72 + h * 8 + 16 * i];
            s = mfma32(kf, qf[i], s);
        }

        // mask (bit[n][m]) + ssq + in-lane pack into PV A-frags
        const unsigned mw = bm32[(size_t)(n0 + nh * 32 + l32) * 128 + mc * 32 + it * 2 + mh];
        bf16x8 af0, af1;
#pragma unroll
        for (int r = 0; r < 16; ++r) {
            const int rp = (r & 3) + 8 * (r >> 2) + 4 * h;   // m-within-32
            const float sm = ((mw >> rp) & 1u) ? s[r] : 0.f;
            ssql += sm * sm;
            if (r < 8) af0[r] = (__bf16)sm; else af1[r - 8] = (__bf16)sm;
        }

        // PV: acc[n][d] += S[n][m] V[m][d]; B-frag m-permutation via 2x b64
#pragma unroll
        for (int dt = 0; dt < 2; ++dt) {
            const int vrow = (dt * 32 + l32) * 72 + mh * 32 + 4 * h;
            bf16x4 lo0 = *(const bf16x4*)&vTl[vrow];
            bf16x4 hi0 = *(const bf16x4*)&vTl[vrow + 8];
            acc[dt] = mfma32(af0, cat44(lo0, hi0), acc[dt]);
            bf16x4 lo1 = *(const bf16x4*)&vTl[vrow + 16];
            bf16x4 hi1 = *(const bf16x4*)&vTl[vrow + 16 + 8];
            acc[dt] = mfma32(af1, cat44(lo1, hi1), acc[dt]);
        }
        __syncthreads();
    }

    // finalize ssq across the two k-halves (same n on lane and lane^32)
    ssql += __shfl_xor(ssql, 32, 64);

    // combine mh halves through LDS (reuses tile memory; loop ended with barrier)
    float* accbuf = (float*)smem;                 // [2][32][64]
    float* ssqbuf = (float*)(smem + 16384);       // [2][32]
    if (mh == 1) {
#pragma unroll
        for (int dt = 0; dt < 2; ++dt)
#pragma unroll
            for (int r = 0; r < 16; ++r) {
                const int rp = (r & 3) + 8 * (r >> 2) + 4 * h;
                accbuf[((size_t)nh * 32 + rp) * 64 + dt * 32 + l32] = acc[dt][r];
            }
        if (h == 0) ssqbuf[nh * 32 + l32] = ssql;
    }
    __syncthreads();
    if (mh == 0) {
        const size_t pbase = ((size_t)(b * 64 + nt) * MC + mc);
#pragma unroll
        for (int dt = 0; dt < 2; ++dt)
#pragma unroll
            for (int r = 0; r < 16; ++r) {
                const int rp = (r & 3) + 8 * (r >> 2) + 4 * h;
                const float v = acc[dt][r] + accbuf[((size_t)nh * 32 + rp) * 64 + dt * 32 + l32];
                g_pac[(pbase * 64 + nh * 32 + rp) * 64 + dt * 32 + l32] = v;
            }
        ssql += ssqbuf[nh * 32 + l32];
        if (h == 0) g_pss[pbase * 64 + nh * 32 + l32] = ssql;
    }
}

// ---------------------------------------------------------------------------
// Phase C: reduce partials + norm + Wu epilogue + output. (unchanged from R5)
// ---------------------------------------------------------------------------
__global__ __launch_bounds__(256) void finish_kernel(
    const void* __restrict__ hid, const void* __restrict__ adj,
    const void* __restrict__ Wui, const void* __restrict__ bui,
    const void* __restrict__ Wuo, const void* __restrict__ buo,
    const void* __restrict__ stepp, void* __restrict__ outp)
{
    const bool F32 = (*(const unsigned*)adj) == 0x3F800000u;

    const int bi = blockIdx.x;
    const int b = bi >> 8;
    const int r16 = bi & 255;
    const int n16 = r16 << 4;
    const int nt = r16 >> 2;
    const int nloc0 = (r16 & 3) << 4;
    const int t = threadIdx.x;
    const int wv = t >> 6, lane = t & 63, l16 = lane & 15, quad = lane >> 4;

    const size_t sbase = ((size_t)(b * 64 + nt) * MC + quad) * 64 + nloc0 + l16;
    float sv = g_pss[sbase];
    sv += __shfl_xor(sv, 16, 64);
    sv += __shfl_xor(sv, 32, 64);
    const float inv = (sv > 0.f) ? __frsqrt_rn(sv) : 0.f;

    float s0[8], s1[8];
#pragma unroll
    for (int j = 0; j < 8; ++j) { s0[j] = 0.f; s1[j] = 0.f; }
#pragma unroll
    for (int mcq = 0; mcq < MC; ++mcq) {
        const size_t abase =
            (((size_t)(b * 64 + nt) * MC + mcq) * 64 + nloc0 + l16) * 64 + quad * 8;
        float4 x0 = *(const float4*)&g_pac[abase];
        float4 x1 = *(const float4*)&g_pac[abase + 4];
        float4 y0 = *(const float4*)&g_pac[abase + 32];
        float4 y1 = *(const float4*)&g_pac[abase + 36];
        s0[0] += x0.x; s0[1] += x0.y; s0[2] += x0.z; s0[3] += x0.w;
        s0[4] += x1.x; s0[5] += x1.y; s0[6] += x1.z; s0[7] += x1.w;
        s1[0] += y0.x; s1[1] += y0.y; s1[2] += y0.z; s1[3] += y0.w;
        s1[4] += y1.x; s1[5] += y1.y; s1[6] += y1.z; s1[7] += y1.w;
    }
    bf16x8 ua0, ua1;
#pragma unroll
    for (int j = 0; j < 8; ++j) {
        ua0[j] = (__bf16)(s0[j] * inv);
        ua1[j] = (__bf16)(s1[j] * inv);
    }

    const bool inter = (n16 < T1c);
    const void* Wu = inter ? Wui : Wuo;
    const void* bu = inter ? bui : buo;
    const float step = ldS(stepp, 0, F32);

    const int ti = wv;
    floatx4 z = {0.f, 0.f, 0.f, 0.f};
    const size_t wrow = (size_t)(ti * 16 + l16) * 64 + quad * 8;
    bf16x8 w0 = ld8(Wu, wrow, F32);
    bf16x8 w1 = ld8(Wu, wrow + 32, F32);
    floatx4 u = mfma16(ua1, w1, mfma16(ua0, w0, z));
    const float buv = ldS(bu, ti * 16 + l16, F32);
#pragma unroll
    for (int r = 0; r < 4; ++r) {
        const size_t idx = ((size_t)(b * Nn + n16 + quad * 4 + r)) * 64 + ti * 16 + l16;
        const float hv = ldS(hid, idx, F32);
        const float dtv = bf2f(g_dt[idx]);
        stOut(outp, idx, hv + step * dtv * (u[r] + buv), F32);
    }
}

extern "C" void kernel_launch(void* const* d_in, const int* in_sizes, int n_in,
                              void* d_out, int out_size, void* d_ws, size_t ws_size,
                              hipStream_t stream)
{
    const void* hid = d_in[0];
    const void* adj = d_in[2];
    const void* Wq  = d_in[3];
    const void* Wk  = d_in[4];
    const void* Wv  = d_in[5];
    const void* Wui = d_in[6];
    const void* bui = d_in[7];
    const void* Wti = d_in[8];
    const void* bti = d_in[9];
    const void* Wuo = d_in[10];
    const void* buo = d_in[11];
    const void* Wto = d_in[12];
    const void* bto = d_in[13];
    const void* stepp = d_in[14];

    qkvt_kernel<<<dim3(Bb * (Nn / 16)), dim3(256), 0, stream>>>(
        hid, adj, Wq, Wk, Wv, Wti, bti, Wto, bto);
    bm_kernel<<<dim3(1024), dim3(256), 0, stream>>>(adj);
    attn_part_kernel<<<dim3(Bb * 64 * MC), dim3(256), 0, stream>>>();
    finish_kernel<<<dim3(Bb * (Nn / 16)), dim3(256), 0, stream>>>(
        hid, adj, Wui, bui, Wuo, buo, stepp, d_out);
}

// Round 7
// 182.850 us; speedup vs baseline: 1.3494x; 1.3494x over previous
//
#include <hip/hip_runtime.h>
#include <hip/hip_bf16.h>
#include <math.h>

#define Bb 4
#define Nn 4096
#define Hh 64
#define T1c 3072
#define MC 4           // split-m chunks (blocks); waves add 2x more split depth

typedef unsigned short ushort_t;
typedef __bf16 bf16x4 __attribute__((ext_vector_type(4)));
typedef __bf16 bf16x8 __attribute__((ext_vector_type(8)));
typedef float floatx4 __attribute__((ext_vector_type(4)));
typedef float floatx16 __attribute__((ext_vector_type(16)));

// Static device scratch, fully rewritten every call (no cross-call state).
__device__ ushort_t g_qw[(size_t)Bb * Nn * Hh];
__device__ ushort_t g_kw[(size_t)Bb * Nn * Hh];
__device__ ushort_t g_vt[(size_t)Bb * Nn * Hh];   // [B][H][N] transposed V
__device__ ushort_t g_dt[(size_t)Bb * Nn * Hh];
__device__ unsigned long long g_bm[(size_t)Nn * (Nn / 64)]; // bit[n][m]: adjacency^T bits
__device__ float    g_pac[(size_t)Bb * 64 * MC * 64 * 64]; // partial acc [b][nt][mc][n][d]
__device__ float    g_pss[(size_t)Bb * 64 * MC * 64];      // partial ssq [b][nt][mc][n]

__device__ __forceinline__ float bf2f(unsigned short u) {
    union { unsigned int i; float f; } c;
    c.i = ((unsigned int)u) << 16;
    return c.f;
}
__device__ __forceinline__ unsigned short f2bf(float f) {
    union { float f; unsigned int i; } c;
    c.f = f;
    unsigned int x = c.i;
    unsigned int r = (x + 0x7fffu + ((x >> 16) & 1u)) >> 16;  // RNE
    return (unsigned short)r;
}

// dtype-adaptive loaders (eidx = element index); F32 is the measured reality.
__device__ __forceinline__ bf16x8 ld8(const void* p, size_t eidx, bool f32) {
    if (f32) {
        const float* fp = (const float*)p + eidx;
        float4 x0 = *(const float4*)fp;
        float4 x1 = *(const float4*)(fp + 4);
        bf16x8 r;
        r[0] = (__bf16)x0.x; r[1] = (__bf16)x0.y; r[2] = (__bf16)x0.z; r[3] = (__bf16)x0.w;
        r[4] = (__bf16)x1.x; r[5] = (__bf16)x1.y; r[6] = (__bf16)x1.z; r[7] = (__bf16)x1.w;
        return r;
    }
    return *(const bf16x8*)((const ushort_t*)p + eidx);
}
__device__ __forceinline__ float ldS(const void* p, size_t eidx, bool f32) {
    return f32 ? ((const float*)p)[eidx] : bf2f(((const ushort_t*)p)[eidx]);
}
__device__ __forceinline__ void stOut(void* p, size_t eidx, float v, bool f32) {
    if (f32) ((float*)p)[eidx] = v;
    else ((ushort_t*)p)[eidx] = f2bf(v);
}

__device__ __forceinline__ floatx4 mfma16(bf16x8 a, bf16x8 b, floatx4 c) {
    return __builtin_amdgcn_mfma_f32_16x16x32_bf16(a, b, c, 0, 0, 0);
}
__device__ __forceinline__ floatx16 mfma32(bf16x8 a, bf16x8 b, floatx16 c) {
    return __builtin_amdgcn_mfma_f32_32x32x16_bf16(a, b, c, 0, 0, 0);
}
__device__ __forceinline__ bf16x8 cat44(bf16x4 lo, bf16x4 hi) {
    bf16x8 r;
    r[0] = lo[0]; r[1] = lo[1]; r[2] = lo[2]; r[3] = lo[3];
    r[4] = hi[0]; r[5] = hi[1]; r[6] = hi[2]; r[7] = hi[3];
    return r;
}

__device__ __forceinline__ float fast_tanh(float x) {
    float e = __expf(-2.0f * fabsf(x));
    float t = (1.0f - e) / (1.0f + e);
    return copysignf(t, x);
}

// ---------------------------------------------------------------------------
// Phase A: q,k,vT,dt. grid B*(N/16)=1024 blocks x 256 thr; waves split by output.
// ---------------------------------------------------------------------------
__global__ __launch_bounds__(256) void qkvt_kernel(
    const void* __restrict__ hid, const void* __restrict__ adj,
    const void* __restrict__ Wq, const void* __restrict__ Wk,
    const void* __restrict__ Wv,
    const void* __restrict__ Wti, const void* __restrict__ bti,
    const void* __restrict__ Wto, const void* __restrict__ bto)
{
    const bool F32 = (*(const unsigned*)adj) == 0x3F800000u;

    const int bi = blockIdx.x;
    const int b = bi >> 8;
    const int n16 = (bi & 255) << 4;
    const int t = threadIdx.x;
    const int wv = t >> 6, lane = t & 63, l16 = lane & 15, quad = lane >> 4;
    const bool inter = (n16 < T1c);

    const void* W = (wv == 0) ? Wq : (wv == 1) ? Wk : (wv == 2) ? Wv
                    : (inter ? Wti : Wto);
    const void* bt = inter ? bti : bto;

    const size_t hbase = ((size_t)(b * Nn + n16 + l16)) * Hh + quad * 8;
    bf16x8 a0 = ld8(hid, hbase, F32);
    bf16x8 a1 = ld8(hid, hbase + 32, F32);
    floatx4 z = {0.f, 0.f, 0.f, 0.f};

    floatx4 c[4];
#pragma unroll
    for (int ti = 0; ti < 4; ++ti) {
        const size_t wrow = (size_t)(ti * 16 + l16) * 64 + quad * 8;
        bf16x8 w0 = ld8(W, wrow, F32);
        bf16x8 w1 = ld8(W, wrow + 32, F32);
        c[ti] = mfma16(a1, w1, mfma16(a0, w0, z));
    }

    if (wv == 0 || wv == 1) {
        ushort_t* dst = (wv == 0) ? g_qw : g_kw;
#pragma unroll
        for (int ti = 0; ti < 4; ++ti)
#pragma unroll
            for (int r = 0; r < 4; ++r)
                dst[((size_t)(b * Nn + n16 + quad * 4 + r)) * 64 + ti * 16 + l16] = f2bf(c[ti][r]);
    } else if (wv == 2) {
#pragma unroll
        for (int ti = 0; ti < 4; ++ti) {
            uint2 pk;
            pk.x = (unsigned)f2bf(c[ti][0]) | ((unsigned)f2bf(c[ti][1]) << 16);
            pk.y = (unsigned)f2bf(c[ti][2]) | ((unsigned)f2bf(c[ti][3]) << 16);
            *(uint2*)&g_vt[((size_t)(b * 64 + ti * 16 + l16)) * Nn + n16 + quad * 4] = pk;
        }
    } else {
#pragma unroll
        for (int ti = 0; ti < 4; ++ti) {
            const float btv = ldS(bt, ti * 16 + l16, F32);
#pragma unroll
            for (int r = 0; r < 4; ++r)
                g_dt[((size_t)(b * Nn + n16 + quad * 4 + r)) * 64 + ti * 16 + l16] =
                    f2bf(fast_tanh(0.5f * (c[ti][r] + btv)));
        }
    }
}

// ---------------------------------------------------------------------------
// Phase A2: transposed adjacency bitmask, bit[n][m] = (adjacency[m][n] != 0).
// Transpose-by-accumulation: lane = n (coalesced dword loads); each lane
// privately ORs bit j for row m0+j over 64 independent loads (no ballot,
// unroll 8 keeps ~8 loads in flight). Block (mt,nc) reads its 64x256 fp32
// tile exactly once -> FETCH = one full adjacency pass (67 MB).
// grid 1024 blocks x 256 thr.
// ---------------------------------------------------------------------------
__global__ __launch_bounds__(256) void bm_kernel(const void* __restrict__ adj)
{
    const bool F32 = (*(const unsigned*)adj) == 0x3F800000u;
    const int bi = blockIdx.x;
    const int mt = bi & 63;        // m-tile (64 rows -> one u64 word)
    const int nc = bi >> 6;        // n-chunk of 256
    const int n = nc * 256 + threadIdx.x;   // this lane's n (coalesced)
    const int m0 = mt * 64;

    unsigned long long bits = 0ull;
#pragma unroll 8
    for (int j = 0; j < 64; ++j) {
        const float v = ldS(adj, (size_t)(m0 + j) * Nn + n, F32);
        bits |= (unsigned long long)(v != 0.f) << j;
    }
    g_bm[(size_t)n * 64 + mt] = bits;
}

// ---------------------------------------------------------------------------
// Phase B: split-m attention partials, transpose-free.
// S' = K·Q^T via mfma32 (C: lane=n, regs=m) -> masked S packs DIRECTLY into
// PV A-frags in-lane; V B-frags absorb the m-permutation as 2x ds_read_b64.
// grid B*64*MC = 1024 blocks x 256 thr.
// ---------------------------------------------------------------------------
__global__ __launch_bounds__(256, 4) void attn_part_kernel()
{
    __shared__ __align__(16) unsigned char smem[64 * 72 * 2 * 2 + 256];
    ushort_t* kT  = (ushort_t*)smem;            // [64][72] K tile [m][h]
    ushort_t* vTl = kT + 64 * 72;               // [64][72] V^T tile [d][m]
    // after the loop, smem is reused: accbuf [2][32][64] fp32 + ssqbuf [2][32]

    const unsigned* bm32 = (const unsigned*)g_bm;

    const int bi = blockIdx.x;
    const int b  = bi >> 8;          // b-variants 256 apart -> same XCD for L2 reuse
    const int mc = bi & 3;
    const int nt = (bi >> 2) & 63;
    const int n0 = nt << 6;
    const int t = threadIdx.x;
    const int wv = t >> 6, lane = t & 63;
    const int l32 = lane & 31, h = lane >> 5;
    const int nh = wv >> 1, mh = wv & 1;

    // Q fragments (B-operand of K·Q^T): lane = n, k = h*8 + 16*i + e
    bf16x8 qf[4];
#pragma unroll
    for (int i = 0; i < 4; ++i)
        qf[i] = *(const bf16x8*)&g_qw[((size_t)(b * Nn + n0 + nh * 32 + l32)) * 64 + h * 8 + 16 * i];

    floatx16 acc[2];
#pragma unroll
    for (int dt = 0; dt < 2; ++dt)
#pragma unroll
        for (int r = 0; r < 16; ++r) acc[dt][r] = 0.f;
    float ssql = 0.f;

    int srow[2], scol[2];
#pragma unroll
    for (int i = 0; i < 2; ++i) { const int cc = t + 256 * i; srow[i] = cc >> 3; scol[i] = (cc & 7) * 8; }

    for (int it = 0; it < 16; ++it) {
        const int m0 = mc * 1024 + it * 64;

        // stage K-tile and V^T-tile
#pragma unroll
        for (int i = 0; i < 2; ++i) {
            *(bf16x8*)&kT[srow[i] * 72 + scol[i]] =
                *(const bf16x8*)&g_kw[((size_t)(b * Nn + m0 + srow[i])) * 64 + scol[i]];
            *(bf16x8*)&vTl[srow[i] * 72 + scol[i]] =
                *(const bf16x8*)&g_vt[((size_t)(b * 64 + srow[i])) * Nn + m0 + scol[i]];
        }
        __syncthreads();

        // S' = K·Q^T: A = K (lane=m), B = Q (lane=n); D: lane=n, regs=m
        floatx16 s;
#pragma unroll
        for (int r = 0; r < 16; ++r) s[r] = 0.f;
#pragma unroll
        for (int i = 0; i < 4; ++i) {
            bf16x8 kf = *(const bf16x8*)&kT[(mh * 32 + l32) * 72 + h * 8 + 16 * i];
            s = mfma32(kf, qf[i], s);
        }

        // mask (bit[n][m]) + ssq + in-lane pack into PV A-frags
        const unsigned mw = bm32[(size_t)(n0 + nh * 32 + l32) * 128 + mc * 32 + it * 2 + mh];
        bf16x8 af0, af1;
#pragma unroll
        for (int r = 0; r < 16; ++r) {
            const int rp = (r & 3) + 8 * (r >> 2) + 4 * h;   // m-within-32
            const float sm = ((mw >> rp) & 1u) ? s[r] : 0.f;
            ssql += sm * sm;
            if (r < 8) af0[r] = (__bf16)sm; else af1[r - 8] = (__bf16)sm;
        }

        // PV: acc[n][d] += S[n][m] V[m][d]; B-frag m-permutation via 2x b64
#pragma unroll
        for (int dt = 0; dt < 2; ++dt) {
            const int vrow = (dt * 32 + l32) * 72 + mh * 32 + 4 * h;
            bf16x4 lo0 = *(const bf16x4*)&vTl[vrow];
            bf16x4 hi0 = *(const bf16x4*)&vTl[vrow + 8];
            acc[dt] = mfma32(af0, cat44(lo0, hi0), acc[dt]);
            bf16x4 lo1 = *(const bf16x4*)&vTl[vrow + 16];
            bf16x4 hi1 = *(const bf16x4*)&vTl[vrow + 16 + 8];
            acc[dt] = mfma32(af1, cat44(lo1, hi1), acc[dt]);
        }
        __syncthreads();
    }

    // finalize ssq across the two k-halves (same n on lane and lane^32)
    ssql += __shfl_xor(ssql, 32, 64);

    // combine mh halves through LDS (reuses tile memory; loop ended with barrier)
    float* accbuf = (float*)smem;                 // [2][32][64]
    float* ssqbuf = (float*)(smem + 16384);       // [2][32]
    if (mh == 1) {
#pragma unroll
        for (int dt = 0; dt < 2; ++dt)
#pragma unroll
            for (int r = 0; r < 16; ++r) {
                const int rp = (r & 3) + 8 * (r >> 2) + 4 * h;
                accbuf[((size_t)nh * 32 + rp) * 64 + dt * 32 + l32] = acc[dt][r];
            }
        if (h == 0) ssqbuf[nh * 32 + l32] = ssql;
    }
    __syncthreads();
    if (mh == 0) {
        const size_t pbase = ((size_t)(b * 64 + nt) * MC + mc);
#pragma unroll
        for (int dt = 0; dt < 2; ++dt)
#pragma unroll
            for (int r = 0; r < 16; ++r) {
                const int rp = (r & 3) + 8 * (r >> 2) + 4 * h;
                const float v = acc[dt][r] + accbuf[((size_t)nh * 32 + rp) * 64 + dt * 32 + l32];
                g_pac[(pbase * 64 + nh * 32 + rp) * 64 + dt * 32 + l32] = v;
            }
        ssql += ssqbuf[nh * 32 + l32];
        if (h == 0) g_pss[pbase * 64 + nh * 32 + l32] = ssql;
    }
}

// ---------------------------------------------------------------------------
// Phase C: reduce partials + norm + Wu epilogue + output.
// ---------------------------------------------------------------------------
__global__ __launch_bounds__(256) void finish_kernel(
    const void* __restrict__ hid, const void* __restrict__ adj,
    const void* __restrict__ Wui, const void* __restrict__ bui,
    const void* __restrict__ Wuo, const void* __restrict__ buo,
    const void* __restrict__ stepp, void* __restrict__ outp)
{
    const bool F32 = (*(const unsigned*)adj) == 0x3F800000u;

    const int bi = blockIdx.x;
    const int b = bi >> 8;
    const int r16 = bi & 255;
    const int n16 = r16 << 4;
    const int nt = r16 >> 2;
    const int nloc0 = (r16 & 3) << 4;
    const int t = threadIdx.x;
    const int wv = t >> 6, lane = t & 63, l16 = lane & 15, quad = lane >> 4;

    const size_t sbase = ((size_t)(b * 64 + nt) * MC + quad) * 64 + nloc0 + l16;
    float sv = g_pss[sbase];
    sv += __shfl_xor(sv, 16, 64);
    sv += __shfl_xor(sv, 32, 64);
    const float inv = (sv > 0.f) ? __frsqrt_rn(sv) : 0.f;

    float s0[8], s1[8];
#pragma unroll
    for (int j = 0; j < 8; ++j) { s0[j] = 0.f; s1[j] = 0.f; }
#pragma unroll
    for (int mcq = 0; mcq < MC; ++mcq) {
        const size_t abase =
            (((size_t)(b * 64 + nt) * MC + mcq) * 64 + nloc0 + l16) * 64 + quad * 8;
        float4 x0 = *(const float4*)&g_pac[abase];
        float4 x1 = *(const float4*)&g_pac[abase + 4];
        float4 y0 = *(const float4*)&g_pac[abase + 32];
        float4 y1 = *(const float4*)&g_pac[abase + 36];
        s0[0] += x0.x; s0[1] += x0.y; s0[2] += x0.z; s0[3] += x0.w;
        s0[4] += x1.x; s0[5] += x1.y; s0[6] += x1.z; s0[7] += x1.w;
        s1[0] += y0.x; s1[1] += y0.y; s1[2] += y0.z; s1[3] += y0.w;
        s1[4] += y1.x; s1[5] += y1.y; s1[6] += y1.z; s1[7] += y1.w;
    }
    bf16x8 ua0, ua1;
#pragma unroll
    for (int j = 0; j < 8; ++j) {
        ua0[j] = (__bf16)(s0[j] * inv);
        ua1[j] = (__bf16)(s1[j] * inv);
    }

    const bool inter = (n16 < T1c);
    const void* Wu = inter ? Wui : Wuo;
    const void* bu = inter ? bui : buo;
    const float step = ldS(stepp, 0, F32);

    const int ti = wv;
    floatx4 z = {0.f, 0.f, 0.f, 0.f};
    const size_t wrow = (size_t)(ti * 16 + l16) * 64 + quad * 8;
    bf16x8 w0 = ld8(Wu, wrow, F32);
    bf16x8 w1 = ld8(Wu, wrow + 32, F32);
    floatx4 u = mfma16(ua1, w1, mfma16(ua0, w0, z));
    const float buv = ldS(bu, ti * 16 + l16, F32);
#pragma unroll
    for (int r = 0; r < 4; ++r) {
        const size_t idx = ((size_t)(b * Nn + n16 + quad * 4 + r)) * 64 + ti * 16 + l16;
        const float hv = ldS(hid, idx, F32);
        const float dtv = bf2f(g_dt[idx]);
        stOut(outp, idx, hv + step * dtv * (u[r] + buv), F32);
    }
}

extern "C" void kernel_launch(void* const* d_in, const int* in_sizes, int n_in,
                              void* d_out, int out_size, void* d_ws, size_t ws_size,
                              hipStream_t stream)
{
    const void* hid = d_in[0];
    const void* adj = d_in[2];
    const void* Wq  = d_in[3];
    const void* Wk  = d_in[4];
    const void* Wv  = d_in[5];
    const void* Wui = d_in[6];
    const void* bui = d_in[7];
    const void* Wti = d_in[8];
    const void* bti = d_in[9];
    const void* Wuo = d_in[10];
    const void* buo = d_in[11];
    const void* Wto = d_in[12];
    const void* bto = d_in[13];
    const void* stepp = d_in[14];

    qkvt_kernel<<<dim3(Bb * (Nn / 16)), dim3(256), 0, stream>>>(
        hid, adj, Wq, Wk, Wv, Wti, bti, Wto, bto);
    bm_kernel<<<dim3(1024), dim3(256), 0, stream>>>(adj);
    attn_part_kernel<<<dim3(Bb * 64 * MC), dim3(256), 0, stream>>>();
    finish_kernel<<<dim3(Bb * (Nn / 16)), dim3(256), 0, stream>>>(
        hid, adj, Wui, bui, Wuo, buo, stepp, d_out);
}